// Round 1
// baseline (5222.493 us; speedup 1.0000x reference)
//
#include <hip/hip_runtime.h>

// GRU (Flax GRUCell), B=64 T=512 D=512 H=512, fp32 in/out, fp16 MFMA compute.
//
// Decomposition: 4 batch-groups x 16 batches. Each group = 32 blocks; block
// owns 16 output columns and keeps its Wh/Wi column slices in LDS (fp16,
// XOR-swizzled for conflict-free ds_read_b128). Per time step, blocks of a
// group exchange h via a double-buffered global fp16 buffer + a monotonic
// atomic counter barrier. 128 blocks, 137KB LDS -> 1 block/CU, all resident.

#define BSZ 64
#define TLEN 512
#define DDIM 512
#define HDIM 512
#define NGRP 4
#define PBLK 32
#define MB 16

typedef _Float16 half8 __attribute__((ext_vector_type(8)));
typedef _Float16 half4v __attribute__((ext_vector_type(4)));
typedef float f32x4 __attribute__((ext_vector_type(4)));

__device__ __forceinline__ float sigmf(float v) { return 1.f / (1.f + __expf(-v)); }

// ---------------- setup: fp32->fp16 convert, weight transpose, zero exch/ctr
__global__ void gru_setup(const float* __restrict__ x, const float* __restrict__ Wi,
                          const float* __restrict__ Wh, _Float16* __restrict__ xb,
                          _Float16* __restrict__ WiT, _Float16* __restrict__ WhT,
                          _Float16* __restrict__ exch, unsigned* __restrict__ ctr) {
  size_t gid = (size_t)blockIdx.x * blockDim.x + threadIdx.x;
  size_t stride = (size_t)gridDim.x * blockDim.x;
  const float4* x4 = (const float4*)x;
  size_t nx4 = (size_t)BSZ * TLEN * DDIM / 4;
  for (size_t i = gid; i < nx4; i += stride) {
    float4 v = x4[i];
    half4v o = {(_Float16)v.x, (_Float16)v.y, (_Float16)v.z, (_Float16)v.w};
    *(half4v*)(xb + 4 * i) = o;
  }
  // WT[n][k] = W[k][n]   (W is [512][1536] row-major; WT is [1536][512])
  for (size_t i = gid; i < (size_t)1536 * 512; i += stride) {
    int n = (int)(i >> 9), k = (int)(i & 511);
    WiT[i] = (_Float16)Wi[(size_t)k * 1536 + n];
    WhT[i] = (_Float16)Wh[(size_t)k * 1536 + n];
  }
  for (size_t i = gid; i < (size_t)2 * BSZ * HDIM; i += stride) exch[i] = (_Float16)0.f;
  for (size_t i = gid; i < 64; i += stride) ctr[i] = 0u;
}

// ---------------- recurrence
// block = 192 threads (3 waves); wave w computes gate w (r,z,n) for the
// block's 16 columns, both the h-part (vs Wh) and x-part (vs Wi) GEMMs.
// Wave 0 then combines gates, updates h, writes outputs + exchange slice.
__global__ __launch_bounds__(192) void gru_rec(
    const _Float16* __restrict__ xb, const _Float16* __restrict__ WiT,
    const _Float16* __restrict__ WhT, const float* __restrict__ bi,
    const float* __restrict__ bhn, _Float16* __restrict__ exch,
    unsigned* __restrict__ ctr, float* __restrict__ out) {
  // LDS: weights (2x48KB), A-tiles (2x16KB), gate exchange (6KB) = 137KB
  __shared__ _Float16 Wh_l[48 * 512];
  __shared__ _Float16 Wi_l[48 * 512];
  __shared__ _Float16 Ah_l[16 * 512];
  __shared__ _Float16 Ax_l[16 * 512];
  __shared__ float Gh_l[3 * 256];
  __shared__ float Gx_l[3 * 256];

  const int tid = threadIdx.x;
  const int lane = tid & 63;
  const int wid = tid >> 6;  // 0..2 = gate index
  const int g = blockIdx.x >> 5;
  const int c0 = (blockIdx.x & 31) * 16;
  unsigned* myctr = ctr + g * 16;  // 64B-separated counters

  // --- load weight slices to LDS, swizzled: phys = row*1024 + (byte ^ ((row&7)<<4))
  for (int c = tid; c < 48 * 64; c += 192) {
    int row = c >> 6, ch = c & 63;
    int gate = row >> 4, j = row & 15;
    int ncol = gate * 512 + c0 + j;  // row in WT[1536][512]
    uint4 vi = *(const uint4*)(WiT + (size_t)ncol * 512 + ch * 8);
    uint4 vh = *(const uint4*)(WhT + (size_t)ncol * 512 + ch * 8);
    int dst = (row << 10) | ((ch << 4) ^ ((row & 7) << 4));
    *(uint4*)((char*)Wi_l + dst) = vi;
    *(uint4*)((char*)Wh_l + dst) = vh;
  }
  // biases for epilogue (wave0 lanes, col j = lane&15)
  const int jj = lane & 15;
  const float bir = bi[c0 + jj];
  const float biz = bi[512 + c0 + jj];
  const float bin_ = bi[1024 + c0 + jj];
  const float bhv = bhn[c0 + jj];
  float hreg[4] = {0.f, 0.f, 0.f, 0.f};  // wave0: h for (m = (lane>>4)*4+q, col jj)
  __syncthreads();

  const int ar = lane & 15;   // A row (batch m) / B row (col n)
  const int kg = lane >> 4;   // k-group
  const int wrow = wid * 16 + ar;

  for (int t = 0; t < TLEN; ++t) {
    // 1. stage A_x(t) (no cross-block dependency -> before barrier spin)
    for (int c = tid; c < 1024; c += 192) {
      int row = c >> 6, ch = c & 63;
      int b = (g << 4) + row;
      uint4 v = *(const uint4*)(xb + (size_t)b * (TLEN * DDIM) + (size_t)t * DDIM + ch * 8);
      *(uint4*)((char*)Ax_l + ((row << 10) | ((ch << 4) ^ ((row & 7) << 4)))) = v;
    }
    // 2. group barrier: wait for all 32 blocks to finish step t-1
    if (tid == 0 && t > 0) {
      unsigned target = (unsigned)(PBLK * t);
      while (__hip_atomic_load(myctr, __ATOMIC_ACQUIRE, __HIP_MEMORY_SCOPE_AGENT) < target) {
      }
    }
    __syncthreads();
    // 3. stage A_h(t) from exchange buffer (read buf = t&1; buf0 pre-zeroed)
    {
      const _Float16* src = exch + (size_t)(t & 1) * (BSZ * HDIM) + (size_t)(g << 4) * HDIM;
      for (int c = tid; c < 1024; c += 192) {
        int row = c >> 6, ch = c & 63;
        uint4 v = *(const uint4*)(src + (size_t)row * HDIM + ch * 8);
        *(uint4*)((char*)Ah_l + ((row << 10) | ((ch << 4) ^ ((row & 7) << 4)))) = v;
      }
    }
    __syncthreads();
    // 4. MFMA: acc_h = h @ Wh_slice[gate], acc_x = x_t @ Wi_slice[gate]
    f32x4 acc_h = {0.f, 0.f, 0.f, 0.f};
    f32x4 acc_x = {0.f, 0.f, 0.f, 0.f};
#pragma unroll
    for (int kt = 0; kt < 16; ++kt) {
      int off = ((kt * 4 + kg) << 4) ^ ((ar & 7) << 4);
      half8 a_h = *(const half8*)((const char*)Ah_l + (ar << 10) + off);
      half8 a_x = *(const half8*)((const char*)Ax_l + (ar << 10) + off);
      half8 b_h = *(const half8*)((const char*)Wh_l + (wrow << 10) + off);
      half8 b_i = *(const half8*)((const char*)Wi_l + (wrow << 10) + off);
      acc_h = __builtin_amdgcn_mfma_f32_16x16x32_f16(a_h, b_h, acc_h, 0, 0, 0);
      acc_x = __builtin_amdgcn_mfma_f32_16x16x32_f16(a_x, b_i, acc_x, 0, 0, 0);
    }
    // 5. publish gate tiles: D layout col=lane&15, row=(lane>>4)*4+q
#pragma unroll
    for (int q = 0; q < 4; ++q) {
      int row = kg * 4 + q;
      Gh_l[wid * 256 + row * 16 + ar] = acc_h[q];
      Gx_l[wid * 256 + row * 16 + ar] = acc_x[q];
    }
    __syncthreads();
    // 6. combine (wave 0): r,z,n -> h_new; write outputs + exchange
    if (wid == 0) {
      _Float16* exw = exch + (size_t)((t + 1) & 1) * (BSZ * HDIM);
#pragma unroll
      for (int q = 0; q < 4; ++q) {
        int m = kg * 4 + q;
        int gi_ = m * 16 + jj;
        float hr = Gh_l[gi_], xr = Gx_l[gi_];
        float hz = Gh_l[256 + gi_], xz = Gx_l[256 + gi_];
        float hn = Gh_l[512 + gi_], xn = Gx_l[512 + gi_];
        float r = sigmf(xr + hr + bir);
        float z = sigmf(xz + hz + biz);
        float pren = xn + bin_ + r * (hn + bhv);
        float n = 2.f / (1.f + __expf(-2.f * pren)) - 1.f;
        float hnew = (1.f - z) * n + z * hreg[q];
        hreg[q] = hnew;
        int b = (g << 4) + m;
        out[(size_t)b * (TLEN * HDIM) + (size_t)t * HDIM + c0 + jj] = hnew;
        exw[(size_t)b * HDIM + c0 + jj] = (_Float16)hnew;
      }
    }
    __syncthreads();  // drains wave0's stores (vmcnt(0) at barrier)
    // 7. signal step completion
    if (tid == 0) {
      __threadfence();
      __hip_atomic_fetch_add(myctr, 1u, __ATOMIC_RELEASE, __HIP_MEMORY_SCOPE_AGENT);
    }
  }
  // carry output: final h
  if (wid == 0) {
#pragma unroll
    for (int q = 0; q < 4; ++q) {
      int m = kg * 4 + q;
      int b = (g << 4) + m;
      out[(size_t)BSZ * TLEN * HDIM + (size_t)b * HDIM + c0 + jj] = hreg[q];
    }
  }
}

extern "C" void kernel_launch(void* const* d_in, const int* in_sizes, int n_in,
                              void* d_out, int out_size, void* d_ws, size_t ws_size,
                              hipStream_t stream) {
  const float* x = (const float*)d_in[0];
  const float* Wi = (const float*)d_in[1];
  const float* bi = (const float*)d_in[2];
  const float* Wh = (const float*)d_in[3];
  const float* bhn = (const float*)d_in[4];
  float* out = (float*)d_out;

  // ws layout (bytes): xb 33554432 | WiT 1572864 | WhT 1572864 | exch 131072 | ctr 256
  char* ws = (char*)d_ws;
  _Float16* xb = (_Float16*)ws;
  _Float16* WiT = (_Float16*)(ws + 33554432);
  _Float16* WhT = (_Float16*)(ws + 35127296);
  _Float16* exch = (_Float16*)(ws + 36700160);
  unsigned* ctr = (unsigned*)(ws + 36831232);

  gru_setup<<<4096, 256, 0, stream>>>(x, Wi, Wh, xb, WiT, WhT, exch, ctr);
  gru_rec<<<NGRP * PBLK, 192, 0, stream>>>(xb, WiT, WhT, bi, bhn, exch, ctr, out);
}

// Round 2
// 2766.788 us; speedup vs baseline: 1.8876x; 1.8876x over previous
//
#include <hip/hip_runtime.h>

// GRU (Flax GRUCell), B=64 T=512 D=512 H=512, fp32 in/out, fp16 MFMA compute.
//
// 4 batch-groups x 16 batches; group = 32 blocks; block owns 16 output
// columns, Wh/Wi column slices LDS-resident (fp16, XOR-swizzled).
// Per step: h exchanged via double-buffered global fp16 buffer using
// RELAXED agent-scope atomics (sc1 bypass loads/stores -> no buffer_inv/
// buffer_wbl2 cache maintenance). Per-block flags (no RMW serialization);
// ordering = data stores -> s_waitcnt vmcnt(0) -> flag store.
// h loads go straight into MFMA A-fragments (no LDS staging for A).
// 128 blocks x 104KB LDS -> 1 block/CU, all co-resident.

#define BSZ 64
#define TLEN 512
#define DDIM 512
#define HDIM 512
#define NGRP 4
#define PBLK 32

typedef _Float16 half8 __attribute__((ext_vector_type(8)));
typedef _Float16 half4v __attribute__((ext_vector_type(4)));
typedef _Float16 half2v __attribute__((ext_vector_type(2)));
typedef float f32x4 __attribute__((ext_vector_type(4)));

__device__ __forceinline__ float sigmf(float v) { return 1.f / (1.f + __expf(-v)); }

// ---------------- setup: fp32->fp16 convert, weight transpose, zero exch/flags
__global__ void gru_setup(const float* __restrict__ x, const float* __restrict__ Wi,
                          const float* __restrict__ Wh, _Float16* __restrict__ xb,
                          _Float16* __restrict__ WiT, _Float16* __restrict__ WhT,
                          _Float16* __restrict__ exch, unsigned* __restrict__ flags) {
  size_t gid = (size_t)blockIdx.x * blockDim.x + threadIdx.x;
  size_t stride = (size_t)gridDim.x * blockDim.x;
  const float4* x4 = (const float4*)x;
  size_t nx4 = (size_t)BSZ * TLEN * DDIM / 4;
  for (size_t i = gid; i < nx4; i += stride) {
    float4 v = x4[i];
    half4v o = {(_Float16)v.x, (_Float16)v.y, (_Float16)v.z, (_Float16)v.w};
    *(half4v*)(xb + 4 * i) = o;
  }
  // WT[n][k] = W[k][n]   (W is [512][1536] row-major; WT is [1536][512])
  for (size_t i = gid; i < (size_t)1536 * 512; i += stride) {
    int n = (int)(i >> 9), k = (int)(i & 511);
    WiT[i] = (_Float16)Wi[(size_t)k * 1536 + n];
    WhT[i] = (_Float16)Wh[(size_t)k * 1536 + n];
  }
  for (size_t i = gid; i < (size_t)2 * BSZ * HDIM; i += stride) exch[i] = (_Float16)0.f;
  for (size_t i = gid; i < (size_t)NGRP * PBLK * 32; i += stride) flags[i] = 0u;
}

// ---------------- recurrence
// 192 threads (3 waves); wave w computes gate w (r,z,n) for the block's 16
// columns: h-part (vs Wh, A from coherent global loads) + x-part (vs Wi,
// A from cached global loads). Wave 0 combines gates, updates h, publishes.
__global__ __launch_bounds__(192, 1) void gru_rec(
    const _Float16* __restrict__ xb, const _Float16* __restrict__ WiT,
    const _Float16* __restrict__ WhT, const float* __restrict__ bi,
    const float* __restrict__ bhn, _Float16* __restrict__ exch,
    unsigned* __restrict__ flags, float* __restrict__ out) {
  // LDS: weights 2x48KB + gate tiles 2x3KB = 104.4KB -> 1 block/CU
  __shared__ _Float16 Wh_l[48 * 512];
  __shared__ _Float16 Wi_l[48 * 512];
  __shared__ float Gh_l[3 * 256];
  __shared__ float Gx_l[3 * 256];

  const int tid = threadIdx.x;
  const int lane = tid & 63;
  const int wid = tid >> 6;  // 0..2 = gate index
  const int g = blockIdx.x >> 5;
  const int blk = blockIdx.x & 31;
  const int c0 = blk * 16;

  // --- load weight slices to LDS, swizzled: phys = row*1024 + (byte ^ ((row&7)<<4))
  for (int c = tid; c < 48 * 64; c += 192) {
    int row = c >> 6, ch = c & 63;
    int gate = row >> 4, j = row & 15;
    int ncol = gate * 512 + c0 + j;  // row in WT[1536][512]
    uint4 vi = *(const uint4*)(WiT + (size_t)ncol * 512 + ch * 8);
    uint4 vh = *(const uint4*)(WhT + (size_t)ncol * 512 + ch * 8);
    int dst = (row << 10) | ((ch << 4) ^ ((row & 7) << 4));
    *(uint4*)((char*)Wi_l + dst) = vi;
    *(uint4*)((char*)Wh_l + dst) = vh;
  }

  const int ar = lane & 15;   // A row (batch m) / B row (col n)
  const int kg = lane >> 4;   // k-group
  const int wrow = wid * 16 + ar;

  // epilogue constants (wave0 lane mapping: batches {m0,m0+8}, cols {cp,cp+1})
  const int m0 = lane >> 3;        // 0..7
  const int cp = (lane & 7) * 2;   // 0,2,...,14
  float bir[2], biz[2], bin_[2], bh[2];
#pragma unroll
  for (int u = 0; u < 2; ++u) {
    bir[u] = bi[c0 + cp + u];
    biz[u] = bi[512 + c0 + cp + u];
    bin_[u] = bi[1024 + c0 + cp + u];
    bh[u] = bhn[c0 + cp + u];
  }
  float hreg[2][2] = {{0.f, 0.f}, {0.f, 0.f}};
  __syncthreads();  // weights staged

  unsigned* const myflags = flags + (size_t)g * PBLK * 32;  // 128B-strided flags
  const int fidx = (lane & 31) * 32;

  for (int t = 0; t < TLEN; ++t) {
    // 1. prefetch x fragments (cached loads; no cross-block dependency)
    half8 a_x[16];
    const half8* xs =
        (const half8*)(xb + (size_t)(g * 16 + ar) * (TLEN * DDIM) + (size_t)t * DDIM);
#pragma unroll
    for (int kt = 0; kt < 16; ++kt) a_x[kt] = xs[kt * 4 + kg];

    // 2. wait for all 32 blocks to have published h(t) (relaxed poll, no fences)
    {
      const unsigned tgt = (unsigned)t;
      while (true) {
        unsigned v = __hip_atomic_load(myflags + fidx, __ATOMIC_RELAXED,
                                       __HIP_MEMORY_SCOPE_AGENT);
        if (__all(v >= tgt)) break;
      }
    }

    // 3. load h fragments straight to registers (coherent bypass loads)
    const unsigned long long* hsrc =
        (const unsigned long long*)(exch + (size_t)(t & 1) * (BSZ * HDIM) +
                                    (size_t)(g * 16 + ar) * HDIM);
    unsigned long long ah[32];
#pragma unroll
    for (int kt = 0; kt < 16; ++kt) {
      ah[2 * kt] = __hip_atomic_load(hsrc + (size_t)(kt * 4 + kg) * 2,
                                     __ATOMIC_RELAXED, __HIP_MEMORY_SCOPE_AGENT);
      ah[2 * kt + 1] = __hip_atomic_load(hsrc + (size_t)(kt * 4 + kg) * 2 + 1,
                                         __ATOMIC_RELAXED, __HIP_MEMORY_SCOPE_AGENT);
    }

    // 4. MFMA: acc_h = h @ Wh_slice[gate], acc_x = x_t @ Wi_slice[gate]
    f32x4 acc_h = {0.f, 0.f, 0.f, 0.f};
    f32x4 acc_x = {0.f, 0.f, 0.f, 0.f};
#pragma unroll
    for (int kt = 0; kt < 16; ++kt) {
      const int off = (((kt * 4 + kg) << 4) ^ ((ar & 7) << 4));
      half8 b_h = *(const half8*)((const char*)Wh_l + (wrow << 10) + off);
      half8 b_i = *(const half8*)((const char*)Wi_l + (wrow << 10) + off);
      struct { unsigned long long lo, hi; } t2 = {ah[2 * kt], ah[2 * kt + 1]};
      half8 a_h;
      __builtin_memcpy(&a_h, &t2, 16);
      acc_x = __builtin_amdgcn_mfma_f32_16x16x32_f16(a_x[kt], b_i, acc_x, 0, 0, 0);
      acc_h = __builtin_amdgcn_mfma_f32_16x16x32_f16(a_h, b_h, acc_h, 0, 0, 0);
    }

    // 5. publish gate tiles (D layout: col=ar, row=kg*4+q)
#pragma unroll
    for (int q = 0; q < 4; ++q) {
      int row = kg * 4 + q;
      Gh_l[wid * 256 + row * 16 + ar] = acc_h[q];
      Gx_l[wid * 256 + row * 16 + ar] = acc_x[q];
    }
    __syncthreads();

    // 6. combine (wave 0): r,z,n -> h_new; write out + exchange; signal
    if (wid == 0) {
      _Float16* exw = exch + (size_t)((t + 1) & 1) * (BSZ * HDIM);
#pragma unroll
      for (int bsel = 0; bsel < 2; ++bsel) {
        const int m = m0 + 8 * bsel;
        float hnew[2];
#pragma unroll
        for (int u = 0; u < 2; ++u) {
          const int gi_ = m * 16 + cp + u;
          float r = sigmf(Gx_l[gi_] + Gh_l[gi_] + bir[u]);
          float z = sigmf(Gx_l[256 + gi_] + Gh_l[256 + gi_] + biz[u]);
          float pren = Gx_l[512 + gi_] + bin_[u] + r * (Gh_l[512 + gi_] + bh[u]);
          float n = 2.f / (1.f + __expf(-2.f * pren)) - 1.f;
          hnew[u] = (1.f - z) * n + z * hreg[bsel][u];
          hreg[bsel][u] = hnew[u];
        }
        const int b = g * 16 + m;
        *(float2*)(out + ((size_t)b * TLEN + t) * HDIM + c0 + cp) =
            make_float2(hnew[0], hnew[1]);
        half2v p2 = {(_Float16)hnew[0], (_Float16)hnew[1]};
        unsigned pu;
        __builtin_memcpy(&pu, &p2, 4);
        __hip_atomic_store((unsigned*)(exw + (size_t)b * HDIM + c0 + cp), pu,
                           __ATOMIC_RELAXED, __HIP_MEMORY_SCOPE_AGENT);
      }
      asm volatile("s_waitcnt vmcnt(0)" ::: "memory");  // data visible at coherence pt
      if (lane == 0)
        __hip_atomic_store(myflags + blk * 32, (unsigned)(t + 1), __ATOMIC_RELAXED,
                           __HIP_MEMORY_SCOPE_AGENT);
    }
  }

  // carry output: final h
  if (wid == 0) {
#pragma unroll
    for (int bsel = 0; bsel < 2; ++bsel) {
      const int m = m0 + 8 * bsel;
      const int b = g * 16 + m;
      *(float2*)(out + (size_t)BSZ * TLEN * HDIM + (size_t)b * HDIM + c0 + cp) =
          make_float2(hreg[bsel][0], hreg[bsel][1]);
    }
  }
}

extern "C" void kernel_launch(void* const* d_in, const int* in_sizes, int n_in,
                              void* d_out, int out_size, void* d_ws, size_t ws_size,
                              hipStream_t stream) {
  const float* x = (const float*)d_in[0];
  const float* Wi = (const float*)d_in[1];
  const float* bi = (const float*)d_in[2];
  const float* Wh = (const float*)d_in[3];
  const float* bhn = (const float*)d_in[4];
  float* out = (float*)d_out;

  // ws layout (bytes): xb 33554432 | WiT 1572864 | WhT 1572864 | exch 131072 | flags 16384
  char* ws = (char*)d_ws;
  _Float16* xb = (_Float16*)ws;
  _Float16* WiT = (_Float16*)(ws + 33554432);
  _Float16* WhT = (_Float16*)(ws + 35127296);
  _Float16* exch = (_Float16*)(ws + 36700160);
  unsigned* flags = (unsigned*)(ws + 36831232);

  gru_setup<<<4096, 256, 0, stream>>>(x, Wi, Wh, xb, WiT, WhT, exch, flags);
  gru_rec<<<NGRP * PBLK, 192, 0, stream>>>(xb, WiT, WhT, bi, bhn, exch, flags, out);
}